// Round 3
// baseline (214.451 us; speedup 1.0000x reference)
//
#include <hip/hip_runtime.h>
#include <stdint.h>

// MHA fused forward: qs@Wqkv -> flash attention (key mask) -> ctx@Wout + bout
// All matmuls via bf16 MFMA 16x16x32 (fp32 accumulate).

typedef unsigned short u16;
typedef uint32_t u32;
typedef u16   u16x4  __attribute__((ext_vector_type(4)));
typedef u16   u16x8  __attribute__((ext_vector_type(8)));
typedef u32   u32x4v __attribute__((ext_vector_type(4)));
typedef __bf16 bf16x8 __attribute__((ext_vector_type(8)));
typedef float f32x4  __attribute__((ext_vector_type(4)));

#define DEV __device__ __forceinline__

DEV u16 f2bf(float f) {            // RNE float->bf16 (bit twiddle; used in epilogues)
    u32 u = __builtin_bit_cast(u32, f);
    u += 0x7fffu + ((u >> 16) & 1u);
    return (u16)(u >> 16);
}

DEV u32 packbf(float a, float b) { // 2 x f32 -> packed bf16x2 (HW cvt, compiler may fuse pk)
    u16 x = __builtin_bit_cast(u16, (__bf16)a);
    u16 y = __builtin_bit_cast(u16, (__bf16)b);
    return (u32)x | ((u32)y << 16);
}

DEV void async16(const void* g, void* l) {   // 16B global->LDS direct (wave-uniform LDS base)
    __builtin_amdgcn_global_load_lds(
        reinterpret_cast<const uint32_t __attribute__((address_space(1)))*>(
            reinterpret_cast<uintptr_t>(g)),
        reinterpret_cast<uint32_t __attribute__((address_space(3)))*>(
            reinterpret_cast<uintptr_t>(l)),
        16, 0, 0);
}

DEV f32x4 mfma16(bf16x8 a, bf16x8 b, f32x4 c) {
    return __builtin_amdgcn_mfma_f32_16x16x32_bf16(a, b, c, 0, 0, 0);
}

// ---------------- prep kernels ----------------

__global__ void k_conv(const float* __restrict__ src, u16* __restrict__ dst) {
    int i = (blockIdx.x * 256 + threadIdx.x) * 4;
    float4 v = *reinterpret_cast<const float4*>(src + i);
    u16x4 o = { f2bf(v.x), f2bf(v.y), f2bf(v.z), f2bf(v.w) };
    *reinterpret_cast<u16x4*>(dst + i) = o;
}

// dst[C x R] = bf16(src[R x C])^T
__global__ void k_tconv(const float* __restrict__ src, u16* __restrict__ dst, int R, int C) {
    __shared__ float t[32][33];
    int c0 = blockIdx.x * 32, r0 = blockIdx.y * 32;
    int tx = threadIdx.x, ty = threadIdx.y;
#pragma unroll
    for (int i = 0; i < 4; ++i)
        t[ty + 8 * i][tx] = src[(size_t)(r0 + ty + 8 * i) * C + c0 + tx];
    __syncthreads();
#pragma unroll
    for (int i = 0; i < 4; ++i)
        dst[(size_t)(c0 + ty + 8 * i) * R + r0 + tx] = f2bf(t[tx][ty + 8 * i]);
}

// additive bias pre-scaled by log2(e) so attention can use exp2 directly
__global__ void k_mask(const int* __restrict__ m, float* __restrict__ b) {
    int i = blockIdx.x * 256 + threadIdx.x;
    b[i] = m[i] ? 0.0f : -1.442695e9f;
}

// ---------------- GEMM: C[MxN] = A[MxK] @ Bt[NxK]^T (+bias) ----------------
// 128x128 tile, BK=32, 4 waves (2x2), global_load_lds staging, 2-bit XOR swizzle.

template <bool OUT_BF16, bool HAS_BIAS>
__global__ __launch_bounds__(256, 2) void k_gemm(
    const u16* __restrict__ A, const u16* __restrict__ Bt,
    void* __restrict__ Cv, const float* __restrict__ bias,
    int M, int N, int K)
{
    __shared__ __attribute__((aligned(16))) u16 As[2][128 * 32];
    __shared__ __attribute__((aligned(16))) u16 Bs[2][128 * 32];

    const int tid = threadIdx.x, wave = tid >> 6, lane = tid & 63;
    const int lh = lane & 15, lg = lane >> 4;
    const int nbn = N >> 7;

    // bijective XCD swizzle
    const int nwg = gridDim.x;
    const int q8 = nwg >> 3, r8 = nwg & 7;
    const int xcd = blockIdx.x & 7, li = blockIdx.x >> 3;
    const int wg = (xcd < r8 ? xcd * (q8 + 1) : r8 * (q8 + 1) + (xcd - r8) * q8) + li;

    const int m0 = (wg / nbn) * 128, n0 = (wg % nbn) * 128;
    const int wm = wave >> 1, wn = wave & 1;
    const int nk = K >> 5;

    auto stage = [&](int buf, int kt) {
#pragma unroll
        for (int i = 0; i < 2; ++i) {
            int c = (wave * 2 + i) * 64 + lane;    // 16B chunk id, 0..511
            int row = c >> 2, cc = c & 3;
            int sc = cc ^ (row & 3);               // pre-swizzled global source
            async16(A  + (size_t)(m0 + row) * K + kt * 32 + sc * 8, &As[buf][(wave * 2 + i) * 512]);
            async16(Bt + (size_t)(n0 + row) * K + kt * 32 + sc * 8, &Bs[buf][(wave * 2 + i) * 512]);
        }
    };

    f32x4 acc[4][4] = {};
    stage(0, 0);
    for (int kt = 0; kt < nk; ++kt) {
        __syncthreads();                       // stage(kt) visible (vmcnt drain at barrier)
        if (kt + 1 < nk) stage((kt + 1) & 1, kt + 1);
        const int buf = kt & 1;
        bf16x8 af[4], bf_[4];
#pragma unroll
        for (int mt = 0; mt < 4; ++mt) {
            int row = wm * 64 + mt * 16 + lh;
            int off = row * 64 + ((lg * 16) ^ ((row & 3) << 4));   // bytes, swizzled read
            af[mt] = __builtin_bit_cast(bf16x8,
                     *reinterpret_cast<const u16x8*>((const char*)&As[buf][0] + off));
        }
#pragma unroll
        for (int nt = 0; nt < 4; ++nt) {
            int row = wn * 64 + nt * 16 + lh;
            int off = row * 64 + ((lg * 16) ^ ((row & 3) << 4));
            bf_[nt] = __builtin_bit_cast(bf16x8,
                      *reinterpret_cast<const u16x8*>((const char*)&Bs[buf][0] + off));
        }
        __builtin_amdgcn_s_setprio(1);
#pragma unroll
        for (int mt = 0; mt < 4; ++mt)
#pragma unroll
            for (int nt = 0; nt < 4; ++nt)
                acc[mt][nt] = mfma16(af[mt], bf_[nt], acc[mt][nt]);
        __builtin_amdgcn_s_setprio(0);
        __syncthreads();                       // all waves done with buf before overwrite
    }

#pragma unroll
    for (int mt = 0; mt < 4; ++mt)
#pragma unroll
        for (int nt = 0; nt < 4; ++nt) {
            int col = n0 + wn * 64 + nt * 16 + lh;
#pragma unroll
            for (int r = 0; r < 4; ++r) {
                int row = m0 + wm * 64 + mt * 16 + 4 * lg + r;   // C/D: row=4*(l>>4)+r, col=l&15
                float v = acc[mt][nt][r];
                if (HAS_BIAS) v += bias[col];
                if (OUT_BF16) ((u16*)Cv)[(size_t)row * N + col] = f2bf(v);
                else          ((float*)Cv)[(size_t)row * N + col] = v;
            }
        }
}

// ---------------- flash attention ----------------
// qkv layout: ((b*2048+s)*48 + c)*64 + a ; c = h (Q), 16+h (K), 32+h (V)
// 512 blocks x 512 threads: one (b,h) x 128-row Q tile, 8 waves x 16 rows. KBLK=64.
// Swapped QK^T (S^T = mfma(K,Q)) -> P is lane-local; PV A-fragment built with an
// 8-shuffle butterfly (no P LDS). No-max softmax (scores bounded, masked->exp2(-1.4e9)=0).

__global__ __launch_bounds__(512, 4) void k_attn(
    const u16* __restrict__ qkv, const float* __restrict__ biasg, u16* __restrict__ ctx)
{
    __shared__ __attribute__((aligned(16))) u16 Ks[2][64 * 64];   // row-major, src-swizzled chunks
    __shared__ __attribute__((aligned(16))) u16 Vt[2][64 * 72];   // [a][k], k XOR-swizzled by a-group

    const int tid = threadIdx.x, wave = tid >> 6, lane = tid & 63;
    const int lh = lane & 15, lg = lane >> 4;
    const bool b5 = lg & 2, b4 = lg & 1;

    const int wg = (blockIdx.x & 7) * 64 + (blockIdx.x >> 3);     // XCD swizzle (512 = 8*64)
    const int qt = wg & 15, bh = wg >> 4;
    const int b = bh >> 4, h = bh & 15;

    const u16* qbase = qkv + ((size_t)b * 2048 * 48 + h) * 64;
    const u16* kbase = qkv + ((size_t)b * 2048 * 48 + 16 + h) * 64;
    const u16* vbase = qkv + ((size_t)b * 2048 * 48 + 32 + h) * 64;
    const float* brow = biasg + b * 2048;

    // staging geometry: thread handles 16B chunk c = tid of the 64x64 tile
    const int srow = wave * 8 + (lane >> 3);     // tile-local row
    const int scc  = lane & 7;                   // 16B chunk within row
    const int ksrc = scc ^ (srow & 7);           // K: pre-swizzled global source chunk
    const int vswz = srow ^ (scc << 3);          // V: swizzled k-position for writes

    // Q fragments: rows qt*128 + wave*16 + lh ; d = ks*32 + lg*8 ..+7
    bf16x8 qf[2];
    {
        int row = qt * 128 + wave * 16 + lh;
        qf[0] = __builtin_bit_cast(bf16x8,
            *reinterpret_cast<const u16x8*>(qbase + (size_t)row * 3072 + lg * 8));
        qf[1] = __builtin_bit_cast(bf16x8,
            *reinterpret_cast<const u16x8*>(qbase + (size_t)row * 3072 + 32 + lg * 8));
    }

    f32x4 oa[4] = {};
    float lsum = 0.0f;

    // prologue: stage tile 0 into buf 0
    {
        async16(kbase + (size_t)srow * 3072 + ksrc * 8, &Ks[0][wave * 512]);
        u16x8 v = *reinterpret_cast<const u16x8*>(vbase + (size_t)srow * 3072 + scc * 8);
#pragma unroll
        for (int j = 0; j < 8; ++j) Vt[0][(scc * 8 + j) * 72 + vswz] = v[j];
    }

    for (int kt = 0; kt < 32; ++kt) {
        __syncthreads();   // stage(kt) landed (vmcnt/lgkm drain); compute(kt-1) done
        const int buf = kt & 1;
        if (kt + 1 < 32) {
            async16(kbase + (size_t)((kt + 1) * 64 + srow) * 3072 + ksrc * 8, &Ks[buf ^ 1][wave * 512]);
            u16x8 v = *reinterpret_cast<const u16x8*>(
                vbase + (size_t)((kt + 1) * 64 + srow) * 3072 + scc * 8);
#pragma unroll
            for (int j = 0; j < 8; ++j) Vt[buf ^ 1][(scc * 8 + j) * 72 + vswz] = v[j];
        }

        // bias (log2e-prescaled) for this lane's k values: k = nt*16 + 4*lg + r
        float4 bias4[4];
#pragma unroll
        for (int nt = 0; nt < 4; ++nt)
            bias4[nt] = *reinterpret_cast<const float4*>(brow + kt * 64 + nt * 16 + 4 * lg);

        // ---- S^T = K Q^T (per wave: 64k x 16q); D: row=k_local(4lg+r), col=q(lh) ----
        f32x4 sa[4] = {};
        __builtin_amdgcn_s_setprio(1);
#pragma unroll
        for (int ks = 0; ks < 2; ++ks) {
            bf16x8 kb[4];
#pragma unroll
            for (int nt = 0; nt < 4; ++nt) {
                int row = nt * 16 + lh;
                int off = row * 64 + (((ks * 4 + lg) ^ (row & 7)) << 3);   // u16 units
                kb[nt] = __builtin_bit_cast(bf16x8,
                         *reinterpret_cast<const u16x8*>(&Ks[buf][off]));
            }
#pragma unroll
            for (int nt = 0; nt < 4; ++nt)
                sa[nt] = mfma16(kb[nt], qf[ks], sa[nt]);   // swapped: D = S^T
        }
        __builtin_amdgcn_s_setprio(0);

        // ---- softmax (no max): e = exp2(s * 0.125*log2e + bias_l2); lane-local ----
        const float SC = 0.1803368801111244f;   // 0.125 * log2(e)
        u32 U[4][2];
#pragma unroll
        for (int nt = 0; nt < 4; ++nt) {
            float e0 = __builtin_exp2f(fmaf(sa[nt][0], SC, bias4[nt].x));
            float e1 = __builtin_exp2f(fmaf(sa[nt][1], SC, bias4[nt].y));
            float e2 = __builtin_exp2f(fmaf(sa[nt][2], SC, bias4[nt].z));
            float e3 = __builtin_exp2f(fmaf(sa[nt][3], SC, bias4[nt].w));
            lsum += (e0 + e1) + (e2 + e3);
            U[nt][0] = packbf(e0, e1);
            U[nt][1] = packbf(e2, e3);
        }

        // ---- butterfly redistribution among the 4 lanes sharing lh ----
        // source (s1,s0)=lg holds k=nt*16+4*lg+{0..3}; target (m1,m0)=lg needs
        // k=ks*32+8*lg+{0..7}. Stage1 (xor32): resident bit5 := nt&1. Stage2 (xor16):
        // resident bit4 := s1. Verified: src k = 32ks+16m1+8m0+4b+2h = target slot.
        u32 V1[2][2][2], F[2][2][2];
        {
            u32 S1[2][2], Y[2][2];
#pragma unroll
            for (int n1 = 0; n1 < 2; ++n1)
#pragma unroll
                for (int hh = 0; hh < 2; ++hh) {
                    S1[n1][hh] = b5 ? U[2 * n1][hh] : U[2 * n1 + 1][hh];
                    Y[n1][hh] = (u32)__shfl_xor((int)S1[n1][hh], 32);
                    u32 kp = b5 ? U[2 * n1 + 1][hh] : U[2 * n1][hh];
                    V1[0][n1][hh] = b5 ? Y[n1][hh] : kp;
                    V1[1][n1][hh] = b5 ? kp : Y[n1][hh];
                }
            u32 S2[2][2], Z[2][2];
#pragma unroll
            for (int n1 = 0; n1 < 2; ++n1)
#pragma unroll
                for (int hh = 0; hh < 2; ++hh) {
                    S2[n1][hh] = b4 ? V1[0][n1][hh] : V1[1][n1][hh];
                    Z[n1][hh] = (u32)__shfl_xor((int)S2[n1][hh], 16);
                    u32 kp = b4 ? V1[1][n1][hh] : V1[0][n1][hh];
                    F[0][n1][hh] = b4 ? Z[n1][hh] : kp;
                    F[1][n1][hh] = b4 ? kp : Z[n1][hh];
                }
        }
        bf16x8 pa[2];
#pragma unroll
        for (int ks = 0; ks < 2; ++ks) {
            u32x4v w = { F[0][ks][0], F[0][ks][1], F[1][ks][0], F[1][ks][1] };
            pa[ks] = __builtin_bit_cast(bf16x8, w);
        }

        // ---- O += P V ----
        __builtin_amdgcn_s_setprio(1);
#pragma unroll
        for (int ks = 0; ks < 2; ++ks) {
            bf16x8 vb[4];
#pragma unroll
            for (int nt = 0; nt < 4; ++nt) {
                int col = nt * 16 + lh;
                int g = (col >> 3) & 7;
                int off = col * 72 + (((ks * 4 + lg) ^ g) << 3);   // u16 units
                vb[nt] = __builtin_bit_cast(bf16x8,
                         *reinterpret_cast<const u16x8*>(&Vt[buf][off]));
            }
#pragma unroll
            for (int nt = 0; nt < 4; ++nt)
                oa[nt] = mfma16(pa[ks], vb[nt], oa[nt]);
        }
        __builtin_amdgcn_s_setprio(0);
    }

    // ---- final denominators: lane sum covers its own k's; reduce the lh-group ----
    float s = lsum;
    s += __shfl_xor(s, 16);
    s += __shfl_xor(s, 32);
    float inv = 1.0f / s;                 // valid for q = lh

    float invq[4];
#pragma unroll
    for (int r = 0; r < 4; ++r)
        invq[r] = __shfl(inv, 4 * lg + r);    // denom for q = 4*lg + r

    // ---- epilogue: O/l -> ctx (b, s, h*64+a) bf16 ----
#pragma unroll
    for (int nt = 0; nt < 4; ++nt)
#pragma unroll
        for (int r = 0; r < 4; ++r) {
            int row = qt * 128 + wave * 16 + 4 * lg + r;
            ctx[(size_t)(b * 2048 + row) * 1024 + h * 64 + nt * 16 + lh] = f2bf(oa[nt][r] * invq[r]);
        }
}

// ---------------- launch ----------------

extern "C" void kernel_launch(void* const* d_in, const int* in_sizes, int n_in,
                              void* d_out, int out_size, void* d_ws, size_t ws_size,
                              hipStream_t stream)
{
    const float* qs   = (const float*)d_in[0];   // (2,2048,1024)
    const int*   mask = (const int*)d_in[1];     // (2,2048)
    const float* Wqkv = (const float*)d_in[2];   // (1024,3072)
    const float* Wout = (const float*)d_in[3];   // (1024,1024)
    const float* bout = (const float*)d_in[4];   // (1024,)
    float* out = (float*)d_out;                  // (2,2048,1024) fp32

    char* ws = (char*)d_ws;
    u16*   qs_bf = (u16*)(ws);                       //  8,388,608 B
    u16*   WqkvT = (u16*)(ws + 8388608);             //  6,291,456 B (3072x1024)
    u16*   WoutT = (u16*)(ws + 14680064);            //  2,097,152 B (1024x1024)
    u16*   qkvb  = (u16*)(ws + 16777216);            // 25,165,824 B (4096x3072)
    u16*   ctxb  = (u16*)(ws + 41943040);            //  8,388,608 B (4096x1024)
    float* biasb = (float*)(ws + 50331648);          //     16,384 B (4096)

    k_conv<<<4096, 256, 0, stream>>>(qs, qs_bf);                       // 4M elems
    k_tconv<<<dim3(96, 32), dim3(32, 8), 0, stream>>>(Wqkv, WqkvT, 1024, 3072);
    k_tconv<<<dim3(32, 32), dim3(32, 8), 0, stream>>>(Wout, WoutT, 1024, 1024);
    k_mask<<<16, 256, 0, stream>>>(mask, biasb);

    k_gemm<true, false><<<768, 256, 0, stream>>>(qs_bf, WqkvT, qkvb, nullptr, 4096, 3072, 1024);
    k_attn<<<512, 512, 0, stream>>>(qkvb, biasb, ctxb);
    k_gemm<false, true><<<256, 256, 0, stream>>>(ctxb, WoutT, out, bout, 4096, 1024, 1024);
}

// Round 4
// 206.113 us; speedup vs baseline: 1.0405x; 1.0405x over previous
//
#include <hip/hip_runtime.h>
#include <stdint.h>

// MHA fused forward: qs@Wqkv -> flash attention (key mask) -> ctx@Wout + bout
// All matmuls via bf16 MFMA 16x16x32 (fp32 accumulate).

typedef unsigned short u16;
typedef uint32_t u32;
typedef u16   u16x4  __attribute__((ext_vector_type(4)));
typedef u16   u16x8  __attribute__((ext_vector_type(8)));
typedef __bf16 bf16x8 __attribute__((ext_vector_type(8)));
typedef float f32x4  __attribute__((ext_vector_type(4)));

#define DEV __device__ __forceinline__

DEV u16 f2bf(float f) {            // RNE float->bf16
    u32 u = __builtin_bit_cast(u32, f);
    u += 0x7fffu + ((u >> 16) & 1u);
    return (u16)(u >> 16);
}

DEV void async16(const void* g, void* l) {   // 16B global->LDS direct (wave-uniform LDS base)
    __builtin_amdgcn_global_load_lds(
        reinterpret_cast<const uint32_t __attribute__((address_space(1)))*>(
            reinterpret_cast<uintptr_t>(g)),
        reinterpret_cast<uint32_t __attribute__((address_space(3)))*>(
            reinterpret_cast<uintptr_t>(l)),
        16, 0, 0);
}

DEV f32x4 mfma16(bf16x8 a, bf16x8 b, f32x4 c) {
    return __builtin_amdgcn_mfma_f32_16x16x32_bf16(a, b, c, 0, 0, 0);
}

// ---------------- prep: fp32->bf16 convert (+ mask bias, log2e-prescaled) ----------------

__global__ void k_prep(const float* __restrict__ qs, u16* __restrict__ qs_bf,
                       const int* __restrict__ m, float* __restrict__ bias) {
    int bid = blockIdx.x;
    if (bid < 4096) {
        int i = (bid * 256 + threadIdx.x) * 4;
        float4 v = *reinterpret_cast<const float4*>(qs + i);
        u16x4 o = { f2bf(v.x), f2bf(v.y), f2bf(v.z), f2bf(v.w) };
        *reinterpret_cast<u16x4*>(qs_bf + i) = o;
    } else {
        int i = (bid - 4096) * 256 + threadIdx.x;
        bias[i] = m[i] ? 0.0f : -1.442695e9f;
    }
}

// both weight transposes in one launch: dst[C x R] = bf16(src[R x C])^T
__global__ void k_tconv(const float* __restrict__ Wqkv, u16* __restrict__ WqkvT,
                        const float* __restrict__ Wout, u16* __restrict__ WoutT) {
    __shared__ float t[32][33];
    int bid = blockIdx.x;
    const float* src; u16* dst; int R, C, bx, by;
    if (bid < 3072) { src = Wqkv; dst = WqkvT; R = 1024; C = 3072; bx = bid % 96; by = bid / 96; }
    else { bid -= 3072; src = Wout; dst = WoutT; R = 1024; C = 1024; bx = bid % 32; by = bid / 32; }
    int c0 = bx * 32, r0 = by * 32;
    int tx = threadIdx.x & 31, ty = threadIdx.x >> 5;
#pragma unroll
    for (int i = 0; i < 4; ++i)
        t[ty + 8 * i][tx] = src[(size_t)(r0 + ty + 8 * i) * C + c0 + tx];
    __syncthreads();
#pragma unroll
    for (int i = 0; i < 4; ++i)
        dst[(size_t)(c0 + ty + 8 * i) * R + r0 + tx] = f2bf(t[tx][ty + 8 * i]);
}

// ---------------- GEMM: C[MxN] = A[MxK] @ Bt[NxK]^T (+bias) ----------------
// BM x 128 tile, BK=32, 512 threads = 8 waves (2x4), each wave (BM/2)x32 output.
// Same 2-barrier double-buffered global_load_lds skeleton as before (proven);
// only the wave decomposition changed (occupancy: 24 waves/CU gemm1, 16 gemm2).

template <int BM, bool OUT_BF16, bool HAS_BIAS>
__global__ __launch_bounds__(512, 4) void k_gemm(
    const u16* __restrict__ A, const u16* __restrict__ Bt,
    void* __restrict__ Cv, const float* __restrict__ bias,
    int M, int N, int K)
{
    constexpr int MT = BM / 32;                       // m-frags per wave (4 or 2)
    __shared__ __attribute__((aligned(16))) u16 As[2][BM * 32];
    __shared__ __attribute__((aligned(16))) u16 Bs[2][128 * 32];

    const int tid = threadIdx.x, wave = tid >> 6, lane = tid & 63;
    const int lh = lane & 15, lg = lane >> 4;
    const int nbn = N >> 7;

    // bijective XCD swizzle
    const int nwg = gridDim.x;
    const int q8 = nwg >> 3, r8 = nwg & 7;
    const int xcd = blockIdx.x & 7, li = blockIdx.x >> 3;
    const int wg = (xcd < r8 ? xcd * (q8 + 1) : r8 * (q8 + 1) + (xcd - r8) * q8) + li;

    const int m0 = (wg / nbn) * BM, n0 = (wg % nbn) * 128;
    const int wm = wave >> 2, wn = wave & 3;          // 2 x 4 waves
    const int nk = K >> 5;

    // staging: chunk c -> (row=c>>2, cc=c&3), pre-swizzled source chunk cc^(row&3)
    const int srow = tid >> 2, scc = tid & 3;
    const int ssc = scc ^ (srow & 3);

    auto stage = [&](int buf, int kt) {
        if (tid < BM * 4)
            async16(A + (size_t)(m0 + srow) * K + kt * 32 + ssc * 8, &As[buf][tid * 8]);
        async16(Bt + (size_t)(n0 + srow) * K + kt * 32 + ssc * 8, &Bs[buf][tid * 8]);
    };

    f32x4 acc[MT][2] = {};
    stage(0, 0);
    for (int kt = 0; kt < nk; ++kt) {
        __syncthreads();                       // stage(kt) visible (vmcnt drain at barrier)
        if (kt + 1 < nk) stage((kt + 1) & 1, kt + 1);
        const int buf = kt & 1;
        bf16x8 af[MT], bf_[2];
#pragma unroll
        for (int mt = 0; mt < MT; ++mt) {
            int row = wm * (BM / 2) + mt * 16 + lh;
            int off = row * 32 + ((lg ^ (row & 3)) * 8);           // u16 units
            af[mt] = __builtin_bit_cast(bf16x8,
                     *reinterpret_cast<const u16x8*>(&As[buf][off]));
        }
#pragma unroll
        for (int nt = 0; nt < 2; ++nt) {
            int row = wn * 32 + nt * 16 + lh;
            int off = row * 32 + ((lg ^ (row & 3)) * 8);
            bf_[nt] = __builtin_bit_cast(bf16x8,
                      *reinterpret_cast<const u16x8*>(&Bs[buf][off]));
        }
        __builtin_amdgcn_s_setprio(1);
#pragma unroll
        for (int mt = 0; mt < MT; ++mt)
#pragma unroll
            for (int nt = 0; nt < 2; ++nt)
                acc[mt][nt] = mfma16(af[mt], bf_[nt], acc[mt][nt]);
        __builtin_amdgcn_s_setprio(0);
        __syncthreads();                       // all waves done with buf before overwrite
    }

#pragma unroll
    for (int mt = 0; mt < MT; ++mt)
#pragma unroll
        for (int nt = 0; nt < 2; ++nt) {
            int col = n0 + wn * 32 + nt * 16 + lh;
#pragma unroll
            for (int r = 0; r < 4; ++r) {
                int row = m0 + wm * (BM / 2) + mt * 16 + 4 * lg + r;   // C/D: row=4*(l>>4)+r
                float v = acc[mt][nt][r];
                if (HAS_BIAS) v += bias[col];
                if (OUT_BF16) ((u16*)Cv)[(size_t)row * N + col] = f2bf(v);
                else          ((float*)Cv)[(size_t)row * N + col] = v;
            }
        }
}

// ---------------- flash attention (round-2 structure, exp2 softmax) ----------------
// qkv layout: ((b*2048+s)*48 + c)*64 + a ; c = h (Q), 16+h (K), 32+h (V)
// 512 blocks x 512 threads: one (b,h) x 128-row Q tile, 8 waves x 16 rows. KBLK=64.
// Double-buffered K/V (one barrier per tile). No-max softmax (scores bounded,
// masked -> exp2(-1.4e9)=0): per-lane partial denominators, one reduction at the end.

__global__ __launch_bounds__(512, 4) void k_attn(
    const u16* __restrict__ qkv, const float* __restrict__ biasg, u16* __restrict__ ctx)
{
    __shared__ __attribute__((aligned(16))) u16 Ks[2][64 * 64];   // row-major, src-swizzled chunks
    __shared__ __attribute__((aligned(16))) u16 Vt[2][64 * 72];   // [a][k], k XOR-swizzled by a-group
    __shared__ __attribute__((aligned(16))) u16 Ps[8 * 16 * 72];  // per-wave P, stride 72

    const int tid = threadIdx.x, wave = tid >> 6, lane = tid & 63;
    const int lh = lane & 15, lg = lane >> 4;

    const int wg = (blockIdx.x & 7) * 64 + (blockIdx.x >> 3);     // XCD swizzle (512 = 8*64)
    const int qt = wg & 15, bh = wg >> 4;
    const int b = bh >> 4, h = bh & 15;

    const u16* qbase = qkv + ((size_t)b * 2048 * 48 + h) * 64;
    const u16* kbase = qkv + ((size_t)b * 2048 * 48 + 16 + h) * 64;
    const u16* vbase = qkv + ((size_t)b * 2048 * 48 + 32 + h) * 64;
    const float* brow = biasg + b * 2048;

    // staging geometry: thread handles 16B chunk c = tid of the 64x64 tile
    const int srow = wave * 8 + (lane >> 3);     // tile-local row
    const int scc  = lane & 7;                   // 16B chunk within row
    const int ksrc = scc ^ (srow & 7);           // K: pre-swizzled global source chunk
    const int vswz = srow ^ (scc << 3);          // V: swizzled k-position for writes

    // Q fragments in registers: rows qt*128 + wave*16 + lh ; d = ks*32 + lg*8 ..+7
    bf16x8 qf[2];
    {
        int row = qt * 128 + wave * 16 + lh;
        qf[0] = __builtin_bit_cast(bf16x8,
            *reinterpret_cast<const u16x8*>(qbase + (size_t)row * 3072 + lg * 8));
        qf[1] = __builtin_bit_cast(bf16x8,
            *reinterpret_cast<const u16x8*>(qbase + (size_t)row * 3072 + 32 + lg * 8));
    }

    f32x4 oa[4] = {};
    float lst[4] = {0.0f, 0.0f, 0.0f, 0.0f};

    u16* Pw = &Ps[wave * 16 * 72];

    // prologue: stage tile 0 into buf 0
    {
        async16(kbase + (size_t)srow * 3072 + ksrc * 8, &Ks[0][wave * 512]);
        u16x8 v = *reinterpret_cast<const u16x8*>(vbase + (size_t)srow * 3072 + scc * 8);
#pragma unroll
        for (int j = 0; j < 8; ++j) Vt[0][(scc * 8 + j) * 72 + vswz] = v[j];
    }

    for (int kt = 0; kt < 32; ++kt) {
        __syncthreads();   // stage(kt) landed (vmcnt/lgkm drain); compute(kt-1) done
        const int buf = kt & 1;
        if (kt + 1 < 32) {
            async16(kbase + (size_t)((kt + 1) * 64 + srow) * 3072 + ksrc * 8, &Ks[buf ^ 1][wave * 512]);
            u16x8 v = *reinterpret_cast<const u16x8*>(
                vbase + (size_t)((kt + 1) * 64 + srow) * 3072 + scc * 8);
#pragma unroll
            for (int j = 0; j < 8; ++j) Vt[buf ^ 1][(scc * 8 + j) * 72 + vswz] = v[j];
        }

        float biasv[4];
#pragma unroll
        for (int nt = 0; nt < 4; ++nt) biasv[nt] = brow[kt * 64 + nt * 16 + lh];

        // ---- S = Q K^T (per wave: 16 x 64) ----
        f32x4 sa[4] = {};
        __builtin_amdgcn_s_setprio(1);
#pragma unroll
        for (int ks = 0; ks < 2; ++ks) {
            bf16x8 kb[4];
#pragma unroll
            for (int nt = 0; nt < 4; ++nt) {
                int row = nt * 16 + lh;
                int off = row * 64 + (((ks * 4 + lg) ^ (row & 7)) << 3);   // u16 units
                kb[nt] = __builtin_bit_cast(bf16x8,
                         *reinterpret_cast<const u16x8*>(&Ks[buf][off]));
            }
#pragma unroll
            for (int nt = 0; nt < 4; ++nt)
                sa[nt] = mfma16(qf[ks], kb[nt], sa[nt]);
        }
        __builtin_amdgcn_s_setprio(0);

        // ---- no-max softmax: e = exp2(s * 0.125*log2e + bias_l2); per-lane denoms ----
        const float SC = 0.1803368801111244f;   // 0.125 * log2(e)
#pragma unroll
        for (int nt = 0; nt < 4; ++nt)
#pragma unroll
            for (int r = 0; r < 4; ++r) {
                float e = __builtin_exp2f(fmaf(sa[nt][r], SC, biasv[nt]));
                lst[r] += e;
                Pw[(4 * lg + r) * 72 + nt * 16 + lh] = f2bf(e);   // D-layout write
            }

        // ---- O += P V ----
        __builtin_amdgcn_s_setprio(1);
#pragma unroll
        for (int ks = 0; ks < 2; ++ks) {
            bf16x8 pa = __builtin_bit_cast(bf16x8,
                        *reinterpret_cast<const u16x8*>(Pw + lh * 72 + ks * 32 + lg * 8));
            bf16x8 vb[4];
#pragma unroll
            for (int nt = 0; nt < 4; ++nt) {
                int col = nt * 16 + lh;
                int g = (col >> 3) & 7;
                int off = col * 72 + (((ks * 4 + lg) ^ g) << 3);   // u16 units
                vb[nt] = __builtin_bit_cast(bf16x8,
                         *reinterpret_cast<const u16x8*>(&Vt[buf][off]));
            }
#pragma unroll
            for (int nt = 0; nt < 4; ++nt)
                oa[nt] = mfma16(pa, vb[nt], oa[nt]);
        }
        __builtin_amdgcn_s_setprio(0);
    }

    // ---- final denominators: one 16-lane reduction per row ----
#pragma unroll
    for (int r = 0; r < 4; ++r) {
        float s = lst[r];
#pragma unroll
        for (int o = 1; o < 16; o <<= 1) s += __shfl_xor(s, o);
        lst[r] = 1.0f / s;
    }

    // ---- epilogue: O/l -> ctx (b, s, h*64+a) bf16 ----
#pragma unroll
    for (int nt = 0; nt < 4; ++nt)
#pragma unroll
        for (int r = 0; r < 4; ++r) {
            int row = qt * 128 + wave * 16 + 4 * lg + r;
            ctx[(size_t)(b * 2048 + row) * 1024 + h * 64 + nt * 16 + lh] = f2bf(oa[nt][r] * lst[r]);
        }
}

// ---------------- launch ----------------

extern "C" void kernel_launch(void* const* d_in, const int* in_sizes, int n_in,
                              void* d_out, int out_size, void* d_ws, size_t ws_size,
                              hipStream_t stream)
{
    const float* qs   = (const float*)d_in[0];   // (2,2048,1024)
    const int*   mask = (const int*)d_in[1];     // (2,2048)
    const float* Wqkv = (const float*)d_in[2];   // (1024,3072)
    const float* Wout = (const float*)d_in[3];   // (1024,1024)
    const float* bout = (const float*)d_in[4];   // (1024,)
    float* out = (float*)d_out;                  // (2,2048,1024) fp32

    char* ws = (char*)d_ws;
    u16*   qs_bf = (u16*)(ws);                       //  8,388,608 B
    u16*   WqkvT = (u16*)(ws + 8388608);             //  6,291,456 B (3072x1024)
    u16*   WoutT = (u16*)(ws + 14680064);            //  2,097,152 B (1024x1024)
    u16*   qkvb  = (u16*)(ws + 16777216);            // 25,165,824 B (4096x3072)
    u16*   ctxb  = (u16*)(ws + 41943040);            //  8,388,608 B (4096x1024)
    float* biasb = (float*)(ws + 50331648);          //     16,384 B (4096)

    k_prep<<<4112, 256, 0, stream>>>(qs, qs_bf, mask, biasb);
    k_tconv<<<4096, 256, 0, stream>>>(Wqkv, WqkvT, Wout, WoutT);

    k_gemm<128, true, false><<<768, 512, 0, stream>>>(qs_bf, WqkvT, qkvb, nullptr, 4096, 3072, 1024);
    k_attn<<<512, 512, 0, stream>>>(qkvb, biasb, ctxb);
    k_gemm<64, false, true><<<512, 512, 0, stream>>>(ctxb, WoutT, out, bout, 4096, 1024, 1024);
}

// Round 5
// 194.292 us; speedup vs baseline: 1.1038x; 1.0608x over previous
//
#include <hip/hip_runtime.h>
#include <stdint.h>

// MHA fused forward: qs@Wqkv -> flash attention (key mask) -> ctx@Wout + bout
// All matmuls via bf16 MFMA 16x16x32 (fp32 accumulate).

typedef unsigned short u16;
typedef uint32_t u32;
typedef u16   u16x4  __attribute__((ext_vector_type(4)));
typedef u16   u16x8  __attribute__((ext_vector_type(8)));
typedef __bf16 bf16x8 __attribute__((ext_vector_type(8)));
typedef float f32x4  __attribute__((ext_vector_type(4)));

#define DEV __device__ __forceinline__

DEV u16 cvt_bf(float f) {          // native f32->bf16 (v_cvt_pk_bf16_f32 class, 1 VALU op)
    return __builtin_bit_cast(u16, (__bf16)f);
}

DEV void async16(const void* g, void* l) {   // 16B global->LDS direct (wave-uniform LDS base)
    __builtin_amdgcn_global_load_lds(
        reinterpret_cast<const uint32_t __attribute__((address_space(1)))*>(
            reinterpret_cast<uintptr_t>(g)),
        reinterpret_cast<uint32_t __attribute__((address_space(3)))*>(
            reinterpret_cast<uintptr_t>(l)),
        16, 0, 0);
}

DEV f32x4 mfma16(bf16x8 a, bf16x8 b, f32x4 c) {
    return __builtin_amdgcn_mfma_f32_16x16x32_bf16(a, b, c, 0, 0, 0);
}

// ---------------- prep: fp32->bf16 convert (+ mask additive bias) ----------------

__global__ void k_prep(const float* __restrict__ qs, u16* __restrict__ qs_bf,
                       const int* __restrict__ m, float* __restrict__ bias) {
    int bid = blockIdx.x;
    if (bid < 4096) {
        int i = (bid * 256 + threadIdx.x) * 4;
        float4 v = *reinterpret_cast<const float4*>(qs + i);
        u16x4 o = { cvt_bf(v.x), cvt_bf(v.y), cvt_bf(v.z), cvt_bf(v.w) };
        *reinterpret_cast<u16x4*>(qs_bf + i) = o;
    } else {
        int i = (bid - 4096) * 256 + threadIdx.x;
        bias[i] = m[i] ? 0.0f : -1.0e9f;
    }
}

// both weight transposes in one launch: dst[C x R] = bf16(src[R x C])^T
__global__ void k_tconv(const float* __restrict__ Wqkv, u16* __restrict__ WqkvT,
                        const float* __restrict__ Wout, u16* __restrict__ WoutT) {
    __shared__ float t[32][33];
    int bid = blockIdx.x;
    const float* src; u16* dst; int R, C, bx, by;
    if (bid < 3072) { src = Wqkv; dst = WqkvT; R = 1024; C = 3072; bx = bid % 96; by = bid / 96; }
    else { bid -= 3072; src = Wout; dst = WoutT; R = 1024; C = 1024; bx = bid % 32; by = bid / 32; }
    int c0 = bx * 32, r0 = by * 32;
    int tx = threadIdx.x & 31, ty = threadIdx.x >> 5;
#pragma unroll
    for (int i = 0; i < 4; ++i)
        t[ty + 8 * i][tx] = src[(size_t)(r0 + ty + 8 * i) * C + c0 + tx];
    __syncthreads();
#pragma unroll
    for (int i = 0; i < 4; ++i)
        dst[(size_t)(c0 + ty + 8 * i) * R + r0 + tx] = cvt_bf(t[tx][ty + 8 * i]);
}

// ---------------- GEMM: C[MxN] = A[MxK] @ Bt[NxK]^T (+bias) ----------------
// BM x 128 tile, BK=32, 512 threads = 8 waves (2x4), each wave (BM/2)x32 output.
// 2-barrier double-buffered global_load_lds skeleton (proven).

template <int BM, bool OUT_BF16, bool HAS_BIAS>
__global__ __launch_bounds__(512, 4) void k_gemm(
    const u16* __restrict__ A, const u16* __restrict__ Bt,
    void* __restrict__ Cv, const float* __restrict__ bias,
    int M, int N, int K)
{
    constexpr int MT = BM / 32;                       // m-frags per wave (4 or 2)
    __shared__ __attribute__((aligned(16))) u16 As[2][BM * 32];
    __shared__ __attribute__((aligned(16))) u16 Bs[2][128 * 32];

    const int tid = threadIdx.x, wave = tid >> 6, lane = tid & 63;
    const int lh = lane & 15, lg = lane >> 4;
    const int nbn = N >> 7;

    // bijective XCD swizzle
    const int nwg = gridDim.x;
    const int q8 = nwg >> 3, r8 = nwg & 7;
    const int xcd = blockIdx.x & 7, li = blockIdx.x >> 3;
    const int wg = (xcd < r8 ? xcd * (q8 + 1) : r8 * (q8 + 1) + (xcd - r8) * q8) + li;

    const int m0 = (wg / nbn) * BM, n0 = (wg % nbn) * 128;
    const int wm = wave >> 2, wn = wave & 3;          // 2 x 4 waves
    const int nk = K >> 5;

    // staging: chunk c -> (row=c>>2, cc=c&3), pre-swizzled source chunk cc^(row&3)
    const int srow = tid >> 2, scc = tid & 3;
    const int ssc = scc ^ (srow & 3);

    auto stage = [&](int buf, int kt) {
        if (tid < BM * 4)
            async16(A + (size_t)(m0 + srow) * K + kt * 32 + ssc * 8, &As[buf][tid * 8]);
        async16(Bt + (size_t)(n0 + srow) * K + kt * 32 + ssc * 8, &Bs[buf][tid * 8]);
    };

    f32x4 acc[MT][2] = {};
    stage(0, 0);
    for (int kt = 0; kt < nk; ++kt) {
        __syncthreads();                       // stage(kt) visible (vmcnt drain at barrier)
        if (kt + 1 < nk) stage((kt + 1) & 1, kt + 1);
        const int buf = kt & 1;
        bf16x8 af[MT], bf_[2];
#pragma unroll
        for (int mt = 0; mt < MT; ++mt) {
            int row = wm * (BM / 2) + mt * 16 + lh;
            int off = row * 32 + ((lg ^ (row & 3)) * 8);           // u16 units
            af[mt] = __builtin_bit_cast(bf16x8,
                     *reinterpret_cast<const u16x8*>(&As[buf][off]));
        }
#pragma unroll
        for (int nt = 0; nt < 2; ++nt) {
            int row = wn * 32 + nt * 16 + lh;
            int off = row * 32 + ((lg ^ (row & 3)) * 8);
            bf_[nt] = __builtin_bit_cast(bf16x8,
                      *reinterpret_cast<const u16x8*>(&Bs[buf][off]));
        }
        __builtin_amdgcn_s_setprio(1);
#pragma unroll
        for (int mt = 0; mt < MT; ++mt)
#pragma unroll
            for (int nt = 0; nt < 2; ++nt)
                acc[mt][nt] = mfma16(af[mt], bf_[nt], acc[mt][nt]);
        __builtin_amdgcn_s_setprio(0);
        __syncthreads();                       // all waves done with buf before overwrite
    }

#pragma unroll
    for (int mt = 0; mt < MT; ++mt)
#pragma unroll
        for (int nt = 0; nt < 2; ++nt) {
            int col = n0 + wn * 32 + nt * 16 + lh;
#pragma unroll
            for (int r = 0; r < 4; ++r) {
                int row = m0 + wm * (BM / 2) + mt * 16 + 4 * lg + r;   // C/D: row=4*(l>>4)+r
                float v = acc[mt][nt][r];
                if (HAS_BIAS) v += bias[col];
                if (OUT_BF16) ((u16*)Cv)[(size_t)row * N + col] = cvt_bf(v);
                else          ((float*)Cv)[(size_t)row * N + col] = v;
            }
        }
}

// ---------------- flash attention (round-2 structure, native exp path) ----------------
// qkv layout: ((b*2048+s)*48 + c)*64 + a ; c = h (Q), 16+h (K), 32+h (V)
// 512 blocks x 512 threads: one (b,h) x 128-row Q tile, 8 waves x 16 rows. KBLK=64.
// Double-buffered K/V (one barrier per tile). No-max softmax (scores bounded,
// masked -> exp(-1e9)=0): per-lane partial denominators, one reduction at the end.

__global__ __launch_bounds__(512, 4) void k_attn(
    const u16* __restrict__ qkv, const float* __restrict__ biasg, u16* __restrict__ ctx)
{
    __shared__ __attribute__((aligned(16))) u16 Ks[2][64 * 64];   // row-major, src-swizzled chunks
    __shared__ __attribute__((aligned(16))) u16 Vt[2][64 * 72];   // [a][k], k XOR-swizzled by a-group
    __shared__ __attribute__((aligned(16))) u16 Ps[8 * 16 * 72];  // per-wave P, stride 72

    const int tid = threadIdx.x, wave = tid >> 6, lane = tid & 63;
    const int lh = lane & 15, lg = lane >> 4;

    const int wg = (blockIdx.x & 7) * 64 + (blockIdx.x >> 3);     // XCD swizzle (512 = 8*64)
    const int qt = wg & 15, bh = wg >> 4;
    const int b = bh >> 4, h = bh & 15;

    const u16* qbase = qkv + ((size_t)b * 2048 * 48 + h) * 64;
    const u16* kbase = qkv + ((size_t)b * 2048 * 48 + 16 + h) * 64;
    const u16* vbase = qkv + ((size_t)b * 2048 * 48 + 32 + h) * 64;
    const float* brow = biasg + b * 2048;

    // staging geometry: thread handles 16B chunk c = tid of the 64x64 tile
    const int srow = wave * 8 + (lane >> 3);     // tile-local row
    const int scc  = lane & 7;                   // 16B chunk within row
    const int ksrc = scc ^ (srow & 7);           // K: pre-swizzled global source chunk
    const int vswz = srow ^ (scc << 3);          // V: swizzled k-position for writes

    // Q fragments in registers: rows qt*128 + wave*16 + lh ; d = ks*32 + lg*8 ..+7
    bf16x8 qf[2];
    {
        int row = qt * 128 + wave * 16 + lh;
        qf[0] = __builtin_bit_cast(bf16x8,
            *reinterpret_cast<const u16x8*>(qbase + (size_t)row * 3072 + lg * 8));
        qf[1] = __builtin_bit_cast(bf16x8,
            *reinterpret_cast<const u16x8*>(qbase + (size_t)row * 3072 + 32 + lg * 8));
    }

    f32x4 oa[4] = {};
    float lst[4] = {0.0f, 0.0f, 0.0f, 0.0f};

    u16* Pw = &Ps[wave * 16 * 72];

    // prologue: stage tile 0 into buf 0
    {
        async16(kbase + (size_t)srow * 3072 + ksrc * 8, &Ks[0][wave * 512]);
        u16x8 v = *reinterpret_cast<const u16x8*>(vbase + (size_t)srow * 3072 + scc * 8);
#pragma unroll
        for (int j = 0; j < 8; ++j) Vt[0][(scc * 8 + j) * 72 + vswz] = v[j];
    }

    for (int kt = 0; kt < 32; ++kt) {
        __syncthreads();   // stage(kt) landed (vmcnt/lgkm drain); compute(kt-1) done
        const int buf = kt & 1;
        if (kt + 1 < 32) {
            async16(kbase + (size_t)((kt + 1) * 64 + srow) * 3072 + ksrc * 8, &Ks[buf ^ 1][wave * 512]);
            u16x8 v = *reinterpret_cast<const u16x8*>(
                vbase + (size_t)((kt + 1) * 64 + srow) * 3072 + scc * 8);
#pragma unroll
            for (int j = 0; j < 8; ++j) Vt[buf ^ 1][(scc * 8 + j) * 72 + vswz] = v[j];
        }

        float biasv[4];
#pragma unroll
        for (int nt = 0; nt < 4; ++nt) biasv[nt] = brow[kt * 64 + nt * 16 + lh];

        // ---- S = Q K^T (per wave: 16 x 64) ----
        f32x4 sa[4] = {};
        __builtin_amdgcn_s_setprio(1);
#pragma unroll
        for (int ks = 0; ks < 2; ++ks) {
            bf16x8 kb[4];
#pragma unroll
            for (int nt = 0; nt < 4; ++nt) {
                int row = nt * 16 + lh;
                int off = row * 64 + (((ks * 4 + lg) ^ (row & 7)) << 3);   // u16 units
                kb[nt] = __builtin_bit_cast(bf16x8,
                         *reinterpret_cast<const u16x8*>(&Ks[buf][off]));
            }
#pragma unroll
            for (int nt = 0; nt < 4; ++nt)
                sa[nt] = mfma16(qf[ks], kb[nt], sa[nt]);
        }
        __builtin_amdgcn_s_setprio(0);

        // ---- no-max softmax: e = __expf(fma(s, 0.125, bias)) — native v_exp path ----
#pragma unroll
        for (int nt = 0; nt < 4; ++nt)
#pragma unroll
            for (int r = 0; r < 4; ++r) {
                float e = __expf(fmaf(sa[nt][r], 0.125f, biasv[nt]));
                lst[r] += e;
                Pw[(4 * lg + r) * 72 + nt * 16 + lh] = cvt_bf(e);   // D-layout write
            }

        // ---- O += P V ----
        __builtin_amdgcn_s_setprio(1);
#pragma unroll
        for (int ks = 0; ks < 2; ++ks) {
            bf16x8 pa = __builtin_bit_cast(bf16x8,
                        *reinterpret_cast<const u16x8*>(Pw + lh * 72 + ks * 32 + lg * 8));
            bf16x8 vb[4];
#pragma unroll
            for (int nt = 0; nt < 4; ++nt) {
                int col = nt * 16 + lh;
                int g = (col >> 3) & 7;
                int off = col * 72 + (((ks * 4 + lg) ^ g) << 3);   // u16 units
                vb[nt] = __builtin_bit_cast(bf16x8,
                         *reinterpret_cast<const u16x8*>(&Vt[buf][off]));
            }
#pragma unroll
            for (int nt = 0; nt < 4; ++nt)
                oa[nt] = mfma16(pa, vb[nt], oa[nt]);
        }
        __builtin_amdgcn_s_setprio(0);
    }

    // ---- final denominators: one 16-lane reduction per row ----
#pragma unroll
    for (int r = 0; r < 4; ++r) {
        float s = lst[r];
#pragma unroll
        for (int o = 1; o < 16; o <<= 1) s += __shfl_xor(s, o);
        lst[r] = 1.0f / s;
    }

    // ---- epilogue: O/l -> ctx (b, s, h*64+a) bf16 ----
#pragma unroll
    for (int nt = 0; nt < 4; ++nt)
#pragma unroll
        for (int r = 0; r < 4; ++r) {
            int row = qt * 128 + wave * 16 + 4 * lg + r;
            ctx[(size_t)(b * 2048 + row) * 1024 + h * 64 + nt * 16 + lh] = cvt_bf(oa[nt][r] * lst[r]);
        }
}

// ---------------- launch ----------------

extern "C" void kernel_launch(void* const* d_in, const int* in_sizes, int n_in,
                              void* d_out, int out_size, void* d_ws, size_t ws_size,
                              hipStream_t stream)
{
    const float* qs   = (const float*)d_in[0];   // (2,2048,1024)
    const int*   mask = (const int*)d_in[1];     // (2,2048)
    const float* Wqkv = (const float*)d_in[2];   // (1024,3072)
    const float* Wout = (const float*)d_in[3];   // (1024,1024)
    const float* bout = (const float*)d_in[4];   // (1024,)
    float* out = (float*)d_out;                  // (2,2048,1024) fp32

    char* ws = (char*)d_ws;
    u16*   qs_bf = (u16*)(ws);                       //  8,388,608 B
    u16*   WqkvT = (u16*)(ws + 8388608);             //  6,291,456 B (3072x1024)
    u16*   WoutT = (u16*)(ws + 14680064);            //  2,097,152 B (1024x1024)
    u16*   qkvb  = (u16*)(ws + 16777216);            // 25,165,824 B (4096x3072)
    u16*   ctxb  = (u16*)(ws + 41943040);            //  8,388,608 B (4096x1024)
    float* biasb = (float*)(ws + 50331648);          //     16,384 B (4096)

    k_prep<<<4112, 256, 0, stream>>>(qs, qs_bf, mask, biasb);
    k_tconv<<<4096, 256, 0, stream>>>(Wqkv, WqkvT, Wout, WoutT);

    k_gemm<128, true, false><<<768, 512, 0, stream>>>(qs_bf, WqkvT, qkvb, nullptr, 4096, 3072, 1024);
    k_attn<<<512, 512, 0, stream>>>(qkvb, biasb, ctxb);
    k_gemm<64, false, true><<<512, 512, 0, stream>>>(ctxb, WoutT, out, bout, 4096, 1024, 1024);
}

// Round 8
// 193.480 us; speedup vs baseline: 1.1084x; 1.0042x over previous
//
#include <hip/hip_runtime.h>
#include <stdint.h>

// MHA fused forward: qs@Wqkv -> flash attention (key mask) -> ctx@Wout + bout
// All matmuls via bf16 MFMA 16x16x32 (fp32 accumulate).

typedef unsigned short u16;
typedef uint32_t u32;
typedef u16   u16x4  __attribute__((ext_vector_type(4)));
typedef u16   u16x8  __attribute__((ext_vector_type(8)));
typedef __bf16 bf16x8 __attribute__((ext_vector_type(8)));
typedef float f32x4  __attribute__((ext_vector_type(4)));

#define DEV __device__ __forceinline__

DEV u16 cvt_bf(float f) {          // native f32->bf16 cast (1 VALU op)
    return __builtin_bit_cast(u16, (__bf16)f);
}

DEV void async16(const void* g, void* l) {   // 16B global->LDS direct (wave-uniform LDS base)
    __builtin_amdgcn_global_load_lds(
        reinterpret_cast<const uint32_t __attribute__((address_space(1)))*>(
            reinterpret_cast<uintptr_t>(g)),
        reinterpret_cast<uint32_t __attribute__((address_space(3)))*>(
            reinterpret_cast<uintptr_t>(l)),
        16, 0, 0);
}

DEV f32x4 mfma16(bf16x8 a, bf16x8 b, f32x4 c) {
    return __builtin_amdgcn_mfma_f32_16x16x32_bf16(a, b, c, 0, 0, 0);
}

// ------- prep (one launch): qs fp32->bf16, mask bias, both weight transposes -------

__global__ void k_prep(const float* __restrict__ qs, u16* __restrict__ qs_bf,
                       const int* __restrict__ m, float* __restrict__ bias,
                       const float* __restrict__ Wqkv, u16* __restrict__ WqkvT,
                       const float* __restrict__ Wout, u16* __restrict__ WoutT) {
    __shared__ float t[32][33];
    int bid = blockIdx.x;
    if (bid < 4096) {                       // qs convert: 4M elems
        int i = (bid * 256 + threadIdx.x) * 4;
        float4 v = *reinterpret_cast<const float4*>(qs + i);
        u16x4 o = { cvt_bf(v.x), cvt_bf(v.y), cvt_bf(v.z), cvt_bf(v.w) };
        *reinterpret_cast<u16x4*>(qs_bf + i) = o;
        return;
    }
    if (bid < 4112) {                       // mask -> additive bias
        int i = (bid - 4096) * 256 + threadIdx.x;
        bias[i] = m[i] ? 0.0f : -1.0e9f;
        return;
    }
    // weight transpose: dst[C x R] = bf16(src[R x C])^T
    const float* src; u16* dst; int R, C, bx, by;
    if (bid < 7184) { int q = bid - 4112; src = Wqkv; dst = WqkvT; R = 1024; C = 3072; bx = q % 96; by = q / 96; }
    else            { int q = bid - 7184; src = Wout; dst = WoutT; R = 1024; C = 1024; bx = q % 32; by = q / 32; }
    int c0 = bx * 32, r0 = by * 32;
    int tx = threadIdx.x & 31, ty = threadIdx.x >> 5;
#pragma unroll
    for (int i = 0; i < 4; ++i)
        t[ty + 8 * i][tx] = src[(size_t)(r0 + ty + 8 * i) * C + c0 + tx];
    __syncthreads();
#pragma unroll
    for (int i = 0; i < 4; ++i)
        dst[(size_t)(c0 + ty + 8 * i) * R + r0 + tx] = cvt_bf(t[tx][ty + 8 * i]);
}

// ---------------- GEMM: C[MxN] = A[MxK] @ Bt[NxK]^T (+bias) ----------------
// BM x BN tile, BK=32, 256 threads = 4 waves (2x2), each wave (BM/2)x(BN/2)
// (m97 density: 16 MFMA / 8 ds_read_b128 at 128x128). Single-barrier 2-phase
// double-buffered loop: at the one (post-MFMA) barrier, all waves are done
// READING buf (lgkmcnt before MFMA) and stage(kt+1)->buf^1 has drained
// (compiler's vmcnt(0) at s_barrier), so next iter may overwrite buf.

template <int BM, int BN, bool OUT_BF16, bool HAS_BIAS>
__global__ __launch_bounds__(256, 3) void k_gemm(
    const u16* __restrict__ A, const u16* __restrict__ Bt,
    void* __restrict__ Cv, const float* __restrict__ bias,
    int M, int N, int K)
{
    constexpr int MT = BM / 32, NT = BN / 32;         // frags per wave
    __shared__ __attribute__((aligned(16))) u16 As[2][BM * 32];
    __shared__ __attribute__((aligned(16))) u16 Bs[2][BN * 32];

    const int tid = threadIdx.x, wave = tid >> 6, lane = tid & 63;
    const int lh = lane & 15, lg = lane >> 4;
    const int nbn = N / BN;

    // bijective XCD swizzle
    const int nwg = gridDim.x;
    const int q8 = nwg >> 3, r8 = nwg & 7;
    const int xcd = blockIdx.x & 7, li = blockIdx.x >> 3;
    const int wg = (xcd < r8 ? xcd * (q8 + 1) : r8 * (q8 + 1) + (xcd - r8) * q8) + li;

    const int m0 = (wg / nbn) * BM, n0 = (wg % nbn) * BN;
    const int wm = wave >> 1, wn = wave & 1;          // 2 x 2 waves
    const int nk = K >> 5;

    auto stage = [&](int buf, int kt) {
#pragma unroll
        for (int i = 0; i < BM / 64; ++i) {           // A: BM*4 chunks of 16B
            int c = i * 256 + tid;
            int row = c >> 2, cc = c & 3;
            int sc = cc ^ (row & 3);                  // pre-swizzled global source
            async16(A + (size_t)(m0 + row) * K + kt * 32 + sc * 8, &As[buf][c * 8]);
        }
#pragma unroll
        for (int i = 0; i < BN / 64; ++i) {           // B: BN*4 chunks
            int c = i * 256 + tid;
            int row = c >> 2, cc = c & 3;
            int sc = cc ^ (row & 3);
            async16(Bt + (size_t)(n0 + row) * K + kt * 32 + sc * 8, &Bs[buf][c * 8]);
        }
    };

    f32x4 acc[MT][NT] = {};
    stage(0, 0);
    __syncthreads();                        // tile 0 landed (vmcnt drain at barrier)
    int buf = 0;
    for (int kt = 0; kt < nk; ++kt) {
        if (kt + 1 < nk) stage(buf ^ 1, kt + 1);
        bf16x8 af[MT], bf_[NT];
#pragma unroll
        for (int mt = 0; mt < MT; ++mt) {
            int row = wm * (BM / 2) + mt * 16 + lh;
            int off = row * 32 + ((lg ^ (row & 3)) * 8);           // u16 units
            af[mt] = __builtin_bit_cast(bf16x8,
                     *reinterpret_cast<const u16x8*>(&As[buf][off]));
        }
#pragma unroll
        for (int nt = 0; nt < NT; ++nt) {
            int row = wn * (BN / 2) + nt * 16 + lh;
            int off = row * 32 + ((lg ^ (row & 3)) * 8);
            bf_[nt] = __builtin_bit_cast(bf16x8,
                      *reinterpret_cast<const u16x8*>(&Bs[buf][off]));
        }
        __builtin_amdgcn_s_setprio(1);
#pragma unroll
        for (int mt = 0; mt < MT; ++mt)
#pragma unroll
            for (int nt = 0; nt < NT; ++nt)
                acc[mt][nt] = mfma16(af[mt], bf_[nt], acc[mt][nt]);
        __builtin_amdgcn_s_setprio(0);
        __syncthreads();                    // reads(buf) done; stage(kt+1) drained
        buf ^= 1;
    }

#pragma unroll
    for (int mt = 0; mt < MT; ++mt)
#pragma unroll
        for (int nt = 0; nt < NT; ++nt) {
            int col = n0 + wn * (BN / 2) + nt * 16 + lh;
#pragma unroll
            for (int r = 0; r < 4; ++r) {
                int row = m0 + wm * (BM / 2) + mt * 16 + 4 * lg + r;   // C/D: row=4*(l>>4)+r
                float v = acc[mt][nt][r];
                if (HAS_BIAS) v += bias[col];
                if (OUT_BF16) ((u16*)Cv)[(size_t)row * N + col] = cvt_bf(v);
                else          ((float*)Cv)[(size_t)row * N + col] = v;
            }
        }
}

// ---------------- flash attention (round-2 structure, native exp path) ----------------
// qkv layout: ((b*2048+s)*48 + c)*64 + a ; c = h (Q), 16+h (K), 32+h (V)
// 512 blocks x 512 threads: one (b,h) x 128-row Q tile, 8 waves x 16 rows. KBLK=64.
// Double-buffered K/V (one barrier per tile). No-max softmax (scores bounded,
// masked -> exp(-1e9)=0): per-lane partial denominators, one reduction at the end.

__global__ __launch_bounds__(512, 4) void k_attn(
    const u16* __restrict__ qkv, const float* __restrict__ biasg, u16* __restrict__ ctx)
{
    __shared__ __attribute__((aligned(16))) u16 Ks[2][64 * 64];   // row-major, src-swizzled chunks
    __shared__ __attribute__((aligned(16))) u16 Vt[2][64 * 72];   // [a][k], k XOR-swizzled by a-group
    __shared__ __attribute__((aligned(16))) u16 Ps[8 * 16 * 72];  // per-wave P, stride 72

    const int tid = threadIdx.x, wave = tid >> 6, lane = tid & 63;
    const int lh = lane & 15, lg = lane >> 4;

    const int wg = (blockIdx.x & 7) * 64 + (blockIdx.x >> 3);     // XCD swizzle (512 = 8*64)
    const int qt = wg & 15, bh = wg >> 4;
    const int b = bh >> 4, h = bh & 15;

    const u16* qbase = qkv + ((size_t)b * 2048 * 48 + h) * 64;
    const u16* kbase = qkv + ((size_t)b * 2048 * 48 + 16 + h) * 64;
    const u16* vbase = qkv + ((size_t)b * 2048 * 48 + 32 + h) * 64;
    const float* brow = biasg + b * 2048;

    // staging geometry: thread handles 16B chunk c = tid of the 64x64 tile
    const int srow = wave * 8 + (lane >> 3);     // tile-local row
    const int scc  = lane & 7;                   // 16B chunk within row
    const int ksrc = scc ^ (srow & 7);           // K: pre-swizzled global source chunk
    const int vswz = srow ^ (scc << 3);          // V: swizzled k-position for writes

    // Q fragments in registers: rows qt*128 + wave*16 + lh ; d = ks*32 + lg*8 ..+7
    bf16x8 qf[2];
    {
        int row = qt * 128 + wave * 16 + lh;
        qf[0] = __builtin_bit_cast(bf16x8,
            *reinterpret_cast<const u16x8*>(qbase + (size_t)row * 3072 + lg * 8));
        qf[1] = __builtin_bit_cast(bf16x8,
            *reinterpret_cast<const u16x8*>(qbase + (size_t)row * 3072 + 32 + lg * 8));
    }

    f32x4 oa[4] = {};
    float lst[4] = {0.0f, 0.0f, 0.0f, 0.0f};

    u16* Pw = &Ps[wave * 16 * 72];

    // prologue: stage tile 0 into buf 0
    {
        async16(kbase + (size_t)srow * 3072 + ksrc * 8, &Ks[0][wave * 512]);
        u16x8 v = *reinterpret_cast<const u16x8*>(vbase + (size_t)srow * 3072 + scc * 8);
#pragma unroll
        for (int j = 0; j < 8; ++j) Vt[0][(scc * 8 + j) * 72 + vswz] = v[j];
    }

    for (int kt = 0; kt < 32; ++kt) {
        __syncthreads();   // stage(kt) landed (vmcnt/lgkm drain); compute(kt-1) done
        const int buf = kt & 1;
        if (kt + 1 < 32) {
            async16(kbase + (size_t)((kt + 1) * 64 + srow) * 3072 + ksrc * 8, &Ks[buf ^ 1][wave * 512]);
            u16x8 v = *reinterpret_cast<const u16x8*>(
                vbase + (size_t)((kt + 1) * 64 + srow) * 3072 + scc * 8);
#pragma unroll
            for (int j = 0; j < 8; ++j) Vt[buf ^ 1][(scc * 8 + j) * 72 + vswz] = v[j];
        }

        float biasv[4];
#pragma unroll
        for (int nt = 0; nt < 4; ++nt) biasv[nt] = brow[kt * 64 + nt * 16 + lh];

        // ---- S = Q K^T (per wave: 16 x 64) ----
        f32x4 sa[4] = {};
        __builtin_amdgcn_s_setprio(1);
#pragma unroll
        for (int ks = 0; ks < 2; ++ks) {
            bf16x8 kb[4];
#pragma unroll
            for (int nt = 0; nt < 4; ++nt) {
                int row = nt * 16 + lh;
                int off = row * 64 + (((ks * 4 + lg) ^ (row & 7)) << 3);   // u16 units
                kb[nt] = __builtin_bit_cast(bf16x8,
                         *reinterpret_cast<const u16x8*>(&Ks[buf][off]));
            }
#pragma unroll
            for (int nt = 0; nt < 4; ++nt)
                sa[nt] = mfma16(qf[ks], kb[nt], sa[nt]);
        }
        __builtin_amdgcn_s_setprio(0);

        // ---- no-max softmax: e = __expf(fma(s, 0.125, bias)) — native v_exp path ----
#pragma unroll
        for (int nt = 0; nt < 4; ++nt)
#pragma unroll
            for (int r = 0; r < 4; ++r) {
                float e = __expf(fmaf(sa[nt][r], 0.125f, biasv[nt]));
                lst[r] += e;
                Pw[(4 * lg + r) * 72 + nt * 16 + lh] = cvt_bf(e);   // D-layout write
            }

        // ---- O += P V ----
        __builtin_amdgcn_s_setprio(1);
#pragma unroll
        for (int ks = 0; ks < 2; ++ks) {
            bf16x8 pa = __builtin_bit_cast(bf16x8,
                        *reinterpret_cast<const u16x8*>(Pw + lh * 72 + ks * 32 + lg * 8));
            bf16x8 vb[4];
#pragma unroll
            for (int nt = 0; nt < 4; ++nt) {
                int col = nt * 16 + lh;
                int g = (col >> 3) & 7;
                int off = col * 72 + (((ks * 4 + lg) ^ g) << 3);   // u16 units
                vb[nt] = __builtin_bit_cast(bf16x8,
                         *reinterpret_cast<const u16x8*>(&Vt[buf][off]));
            }
#pragma unroll
            for (int nt = 0; nt < 4; ++nt)
                oa[nt] = mfma16(pa, vb[nt], oa[nt]);
        }
        __builtin_amdgcn_s_setprio(0);
    }

    // ---- final denominators: one 16-lane reduction per row ----
#pragma unroll
    for (int r = 0; r < 4; ++r) {
        float s = lst[r];
#pragma unroll
        for (int o = 1; o < 16; o <<= 1) s += __shfl_xor(s, o);
        lst[r] = 1.0f / s;
    }

    // ---- epilogue: O/l -> ctx (b, s, h*64+a) bf16 ----
#pragma unroll
    for (int nt = 0; nt < 4; ++nt)
#pragma unroll
        for (int r = 0; r < 4; ++r) {
            int row = qt * 128 + wave * 16 + 4 * lg + r;
            ctx[(size_t)(b * 2048 + row) * 1024 + h * 64 + nt * 16 + lh] = cvt_bf(oa[nt][r] * lst[r]);
        }
}

// ---------------- launch ----------------

extern "C" void kernel_launch(void* const* d_in, const int* in_sizes, int n_in,
                              void* d_out, int out_size, void* d_ws, size_t ws_size,
                              hipStream_t stream)
{
    const float* qs   = (const float*)d_in[0];   // (2,2048,1024)
    const int*   mask = (const int*)d_in[1];     // (2,2048)
    const float* Wqkv = (const float*)d_in[2];   // (1024,3072)
    const float* Wout = (const float*)d_in[3];   // (1024,1024)
    const float* bout = (const float*)d_in[4];   // (1024,)
    float* out = (float*)d_out;                  // (2,2048,1024) fp32

    char* ws = (char*)d_ws;
    u16*   qs_bf = (u16*)(ws);                       //  8,388,608 B
    u16*   WqkvT = (u16*)(ws + 8388608);             //  6,291,456 B (3072x1024)
    u16*   WoutT = (u16*)(ws + 14680064);            //  2,097,152 B (1024x1024)
    u16*   qkvb  = (u16*)(ws + 16777216);            // 25,165,824 B (4096x3072)
    u16*   ctxb  = (u16*)(ws + 41943040);            //  8,388,608 B (4096x1024)
    float* biasb = (float*)(ws + 50331648);          //     16,384 B (4096)

    k_prep<<<8208, 256, 0, stream>>>(qs, qs_bf, mask, biasb, Wqkv, WqkvT, Wout, WoutT);

    k_gemm<128, 128, true, false><<<768, 256, 0, stream>>>(qs_bf, WqkvT, qkvb, nullptr, 4096, 3072, 1024);
    k_attn<<<512, 512, 0, stream>>>(qkvb, biasb, ctxb);
    k_gemm<128, 64, false, true><<<512, 256, 0, stream>>>(ctxb, WoutT, out, bout, 4096, 1024, 1024);
}